// Round 4
// baseline (263.647 us; speedup 1.0000x reference)
//
#include <hip/hip_runtime.h>

// FC_CPPN: per-pixel tiny MLP, ALL float32 (inputs, weights, output).
//  d_in[0]=x[N], [1]=y[N], [2]=r[N], [3]=z[N,8], [4]=W0[8,11], [5]=b0[8],
//  [6]=Wm[8,8], [7]=bm[8], [8]=Wo[3,8], [9]=bo[3], [10]=masks[3,4,2] (int)
// out: float32 [N,3]
//
// Scaled-state formulation: u_l = 2^l * out_l.
//   pre_l   = (Wm*2^-l) u_l + bm          (prep stores 3 scaled Wm copies)
//   u_{l+1} = u_l + 2^l * act(pre_l)       (2^l = 1,2,4 -> inline consts)
//   result  = sigmoid((Wo/8) u_3 + bo)
//
// R4: 2 ADJACENT pixels per thread carried as float2 lanes. Purpose: cut
// vmem instruction count (R2/R3 invariant at 8/pixel -> suspected TA-issue
// bound): x/y/r 6 dword loads -> 3 b64; stores 6 dword -> 3 b64; z 4 b128.
// 16 -> 10 vmem per 2 pixels. float2 math invites v_pk_fma_f32 packing.
//
// ws float layout:
//   [0,88)    W0 (cols 0..7 pre-scaled by 1/Z_SCALE=0.1)
//   [88,96)   b0
//   [96,288)  Wm*2^-l for l=0,1,2 (64 floats each)
//   [288,296) bm
//   [296,320) Wo/8
//   [320,323) bo
// ws int layout: [384,408) funid[l*8 + natural_column] = activation 0..3

__global__ void cppn_prep(const float* __restrict__ W0,
                          const float* __restrict__ b0,
                          const float* __restrict__ Wm,
                          const float* __restrict__ bm,
                          const float* __restrict__ Wo,
                          const float* __restrict__ bo,
                          const int* __restrict__ masks,
                          float* __restrict__ wf,
                          int* __restrict__ wi) {
    int t = threadIdx.x;
    if (t < 88) {
        int k = t % 11;
        wf[t] = W0[t] * (k < 8 ? 0.1f : 1.0f);      // fold z/Z_SCALE
    } else if (t < 96) {
        wf[t] = b0[t - 88];
    } else if (t < 288) {
        int j = t - 96;
        int l = j >> 6;                              // which scaled copy
        float s = (l == 0) ? 1.0f : (l == 1 ? 0.5f : 0.25f);
        wf[96 + j] = Wm[j & 63] * s;
    } else if (t < 296) {
        wf[t] = bm[t - 288];
    } else if (t < 320) {
        wf[t] = Wo[t - 296] * 0.125f;                // fold /8
    } else if (t < 323) {
        wf[t] = bo[t - 320];
    } else if (t < 323 + 24) {
        int j = t - 323;          // j = l*8 + f*2 + slot  (masks flat [3,4,2])
        // int64-masks hedge: valid int32 masks have every odd entry >= 1;
        // int64-as-int32 has all odd words == 0 (high words, little-endian).
        bool is64 = true;
        for (int q = 1; q < 24; q += 2) is64 = is64 && (masks[q] == 0);
        int c = is64 ? masks[2 * j] : masks[j];      // natural column 0..7
        int l = j >> 3;
        int f = (j & 7) >> 1;                        // activation id
        wi[384 + l * 8 + c] = f;
    }
}

static __device__ __forceinline__ float2 fma2(float s, float2 a, float2 c) {
    return make_float2(fmaf(s, a.x, c.x), fmaf(s, a.y, c.y));
}

__global__ __launch_bounds__(256) void cppn_main(
    const float* __restrict__ xb,
    const float* __restrict__ yb,
    const float* __restrict__ rb,
    const float4* __restrict__ z4,         // 8 f32 per pixel = two float4
    const float* __restrict__ wf,          // ws floats (uniform -> s_load)
    const int* __restrict__ fid,           // funid base (ws ints + 384)
    float* __restrict__ out,
    int n) {
    int t = blockIdx.x * 256 + threadIdx.x;    // thread id
    int p0 = 2 * t;                            // first of two adjacent pixels
    if (p0 >= n) return;
    bool ok1 = (p0 + 1) < n;

    // ---- loads: 4x b128 (z) + 3x b64 (x,y,r) ----
    float4 za = z4[4 * t];
    float4 zc = z4[4 * t + 1];
    float4 zbv, zdv;
    float2 xv, yv, rv;
    if (ok1) {
        zbv = z4[4 * t + 2];
        zdv = z4[4 * t + 3];
        xv = ((const float2*)xb)[t];
        yv = ((const float2*)yb)[t];
        rv = ((const float2*)rb)[t];
    } else {
        zbv = za; zdv = zc;
        xv = make_float2(xb[p0], xb[p0]);
        yv = make_float2(yb[p0], yb[p0]);
        rv = make_float2(rb[p0], rb[p0]);
    }

    // in2[k] = {pixel p0 feature k, pixel p0+1 feature k}
    float2 in2[11];
    in2[0] = make_float2(za.x, zbv.x);
    in2[1] = make_float2(za.y, zbv.y);
    in2[2] = make_float2(za.z, zbv.z);
    in2[3] = make_float2(za.w, zbv.w);
    in2[4] = make_float2(zc.x, zdv.x);
    in2[5] = make_float2(zc.y, zdv.y);
    in2[6] = make_float2(zc.z, zdv.z);
    in2[7] = make_float2(zc.w, zdv.w);
    in2[8]  = xv;
    in2[9]  = yv;
    in2[10] = rv;

    float2 u[8];
#pragma unroll
    for (int h = 0; h < 8; ++h) {
        float2 acc = make_float2(wf[88 + h], wf[88 + h]);
#pragma unroll
        for (int k = 0; k < 11; ++k)
            acc = fma2(wf[h * 11 + k], in2[k], acc);
        u[h] = acc;
    }

#pragma unroll
    for (int l = 0; l < 3; ++l) {
        const float* W = wf + 96 + 64 * l;            // Wm * 2^-l
        const float scale = (l == 0) ? 1.0f : (l == 1 ? 2.0f : 4.0f);
        float2 p[8];
#pragma unroll
        for (int h = 0; h < 8; ++h) {
            float2 acc = make_float2(wf[288 + h], wf[288 + h]);
#pragma unroll
            for (int k = 0; k < 8; ++k)
                acc = fma2(W[h * 8 + k], u[k], acc);
            p[h] = acc;
        }
#pragma unroll
        for (int h = 0; h < 8; ++h) {
            // wave-uniform activation id -> scalar branch, no divergence;
            // one branch serves both pixels.
            int f = __builtin_amdgcn_readfirstlane(fid[l * 8 + h]);
            float2 v;
            if (f == 0) {
                v = make_float2(__sinf(p[h].x), __sinf(p[h].y));
            } else if (f == 1) {
                v = make_float2(
                    0.3989422804014327f * __expf(-0.5f * p[h].x * p[h].x),
                    0.3989422804014327f * __expf(-0.5f * p[h].y * p[h].y));
            } else if (f == 2) {
                // tanh(t) = 1 - 2/(e^{2t}+1); e=inf -> rcp=0 -> v=1 (safe)
                float ea = __expf(2.0f * p[h].x);
                float eb = __expf(2.0f * p[h].y);
                v = make_float2(
                    fmaf(-2.0f, __builtin_amdgcn_rcpf(ea + 1.0f), 1.0f),
                    fmaf(-2.0f, __builtin_amdgcn_rcpf(eb + 1.0f), 1.0f));
            } else {
                v = p[h];   // identity
            }
            u[h] = fma2(scale, v, u[h]);              // inline-const scale
        }
    }

    // ---- output head: sigmoid((Wo/8) u + bo), 6 floats -> 3x b64 ----
    float2 o[3];
#pragma unroll
    for (int j = 0; j < 3; ++j) {
        float2 acc = make_float2(wf[320 + j], wf[320 + j]);
#pragma unroll
        for (int k = 0; k < 8; ++k)
            acc = fma2(wf[296 + j * 8 + k], u[k], acc);
        o[j] = make_float2(
            __builtin_amdgcn_rcpf(1.0f + __expf(-acc.x)),
            __builtin_amdgcn_rcpf(1.0f + __expf(-acc.y)));
    }

    if (ok1) {
        float2* o2 = (float2*)out;                    // byte offset 24t, 8-aligned
        o2[3 * t]     = make_float2(o[0].x, o[1].x);  // p0: c0,c1
        o2[3 * t + 1] = make_float2(o[2].x, o[0].y);  // p0:c2, p1:c0
        o2[3 * t + 2] = make_float2(o[1].y, o[2].y);  // p1: c1,c2
    } else {
        out[3 * p0]     = o[0].x;
        out[3 * p0 + 1] = o[1].x;
        out[3 * p0 + 2] = o[2].x;
    }
}

extern "C" void kernel_launch(void* const* d_in, const int* in_sizes, int n_in,
                              void* d_out, int out_size, void* d_ws, size_t ws_size,
                              hipStream_t stream) {
    const float* xb = (const float*)d_in[0];
    const float* yb = (const float*)d_in[1];
    const float* rb = (const float*)d_in[2];
    const float* zb = (const float*)d_in[3];
    const float* W0 = (const float*)d_in[4];
    const float* b0 = (const float*)d_in[5];
    const float* Wm = (const float*)d_in[6];
    const float* bm = (const float*)d_in[7];
    const float* Wo = (const float*)d_in[8];
    const float* bo = (const float*)d_in[9];
    const int* masks = (const int*)d_in[10];

    float* wf = (float*)d_ws;
    int*   wi = (int*)d_ws;

    int n = in_sizes[0];   // N pixels

    cppn_prep<<<1, 512, 0, stream>>>(W0, b0, Wm, bm, Wo, bo, masks, wf, wi);
    int per_block = 512;   // 256 threads x 2 adjacent pixels
    cppn_main<<<(n + per_block - 1) / per_block, 256, 0, stream>>>(
        xb, yb, rb, (const float4*)zb, wf, wi + 384,
        (float*)d_out, n);
}